// Round 1
// baseline (177.747 us; speedup 1.0000x reference)
//
#include <hip/hip_runtime.h>

// F0 via autocorrelation argmax — round 14: worklist pipeline.
//   SR=16000, HOP=256, FRAME_LEN=512, pad=256, T=163840, B=64, n_frames=641
//   lags p in [32,256). argmax of RAW autocorrelation == reference argmax.
//
// r13 counters: Occupancy 19% (<< LDS cap 75%), VALUBusy 29%, MfmaUtil 7%,
// HBM 4%. Per-CU issue work ~12us vs 74us measured -> CUs are starved for
// workgroups (10256 single-shot blocks, 7.2ns/WG). Fix: few long blocks.
//
// Pipeline (stream-ordered, graph-capture safe):
//   f0_zero : reset worklist counters (device globals, no workspace).
//   f0_t1   : 1536 blocks x 4 waves (6 blocks/CU, all resident), each wave
//             loops 7 contiguous frames, tier-1 only (16 MFMA, E1 gate).
//             No fp64/tier-2 code -> <=64 VGPR, no spill risk (r11/12 trap
//             was tiers-2/3 inside a loop). Reject -> atomic push list2.
//   f0_t2   : 512 blocks grid-stride over list2 (~15%): exact tier-2
//             numerics (2-chain hi*hi + hi*lo + lo*hi chains, E2 gate).
//             Reject -> push list3.
//   f0_t3   : 128 blocks grid-stride over list3 (~1-2%): exact fp64 tile,
//             compiled standalone (no 64-VGPR pressure -> no spills).
//
// GEMM cast (validated r8-r13, absmax 0.0): y = frame zero-extended,
//   A[m,k]=y[k-16m], B[k,n]=y[k+32+n] => D[m,n]=AC[32+16m+n]
//   16 mfma_f32_16x16x32_f16 (K=512), two parity LDS copies for B-align.
// Tier gates unchanged: E1 = 2^-10*Q + 0.05, E2 = 1e-4*Q + 0.02.

#define SR_F 16000.0f
#define HOP 256
#define FRAME_LEN 512
#define PAD 256
#define T_LEN 163840
#define N_FRAMES 641
#define TOTAL (64 * N_FRAMES)      // 41024
#define MIN_PERIOD 32
#define N_LAGS 224

#define A_BLOCKS 1536              // = 256 CUs * 6 blocks (12.8KB LDS each)
#define A_WPB 4
#define A_WAVES (A_BLOCKS * A_WPB) // 6144
#define A_CHUNK 7                  // 6144*7 = 43008 >= 41024 (bound-checked)

#define B_BLOCKS 512
#define B_WPB 4
#define B_WAVES (B_BLOCKS * B_WPB) // 2048

#define C_BLOCKS 128
#define C_WPB 4
#define C_WAVES (C_BLOCKS * C_WPB) // 512

typedef _Float16 half8 __attribute__((ext_vector_type(8)));
typedef float floatx4 __attribute__((ext_vector_type(4)));

__device__ unsigned int g_cnt2;
__device__ unsigned int g_cnt3;
__device__ unsigned int g_lst2[TOTAL];
__device__ unsigned int g_lst3[TOTAL];

__device__ __forceinline__ int swz(int q) { return q ^ ((q >> 3) & 7); }

__device__ __forceinline__ unsigned int pkh(float a, float b) {
    unsigned short ha = __builtin_bit_cast(unsigned short, (_Float16)a);
    unsigned short hb = __builtin_bit_cast(unsigned short, (_Float16)b);
    return (unsigned int)ha | ((unsigned int)hb << 16);
}

// stage parity copies: even (elem e = Y[e-240]) + odd (elem e = Y[e-239])
__device__ __forceinline__ void write_copies(unsigned int* e, unsigned int* o,
                                             unsigned int u10, unsigned int u11,
                                             unsigned int u20, unsigned int u21,
                                             int lane) {
    e[120 + 2*lane] = u10;  e[121 + 2*lane] = u11;
    e[248 + 2*lane] = u20;  e[249 + 2*lane] = u21;
    unsigned int a  = __shfl(u10, (lane + 1) & 63);
    unsigned int bb = __shfl(u20, (lane + 1) & 63);
    unsigned int n1 = (lane == 63) ? bb : a;
    unsigned int n2 = (lane == 63) ? 0u : bb;
    o[120 + 2*lane] = (u10 >> 16) | (u11 << 16);
    o[121 + 2*lane] = (u11 >> 16) | (n1 << 16);
    o[248 + 2*lane] = (u20 >> 16) | (u21 << 16);
    o[249 + 2*lane] = (u21 >> 16) | (n2 << 16);
    if (lane == 0) o[119] = u10 << 16;   // {Y[-1]=0, Y[0]}
}

// tier-1 hi*hi accumulation, exact r13 association (2 chains then add)
__device__ __forceinline__ floatx4 mfma16_2chain(const unsigned int* ye,
                                                 const unsigned int* ybh,
                                                 int wA0, int wB0) {
    floatx4 acc0 = {0.f, 0.f, 0.f, 0.f};
    floatx4 acc1 = {0.f, 0.f, 0.f, 0.f};
    #pragma unroll
    for (int c = 0; c < 16; c += 2) {
        uint4 au0 = *(const uint4*)(ye + (wA0 + 16*c));
        const unsigned int* pb0 = ybh + (wB0 + 16*c);
        uint4 bu0; bu0.x=pb0[0]; bu0.y=pb0[1]; bu0.z=pb0[2]; bu0.w=pb0[3];
        uint4 au1 = *(const uint4*)(ye + (wA0 + 16*(c+1)));
        const unsigned int* pb1 = ybh + (wB0 + 16*(c+1));
        uint4 bu1; bu1.x=pb1[0]; bu1.y=pb1[1]; bu1.z=pb1[2]; bu1.w=pb1[3];
        acc0 = __builtin_amdgcn_mfma_f32_16x16x32_f16(
            __builtin_bit_cast(half8, au0), __builtin_bit_cast(half8, bu0),
            acc0, 0, 0, 0);
        acc1 = __builtin_amdgcn_mfma_f32_16x16x32_f16(
            __builtin_bit_cast(half8, au1), __builtin_bit_cast(half8, bu1),
            acc1, 0, 0, 0);
    }
    return acc0 + acc1;
}

// one sequential 16-MFMA correction chain (A from pa, B from pb-parity)
__device__ __forceinline__ floatx4 mfma16_chain(floatx4 acc,
                                                const unsigned int* pa,
                                                const unsigned int* pb,
                                                int wA0, int wB0) {
    #pragma unroll
    for (int c = 0; c < 16; ++c) {
        uint4 au = *(const uint4*)(pa + (wA0 + 16*c));
        const unsigned int* p = pb + (wB0 + 16*c);
        uint4 bu; bu.x = p[0]; bu.y = p[1]; bu.z = p[2]; bu.w = p[3];
        acc = __builtin_amdgcn_mfma_f32_16x16x32_f16(
            __builtin_bit_cast(half8, au), __builtin_bit_cast(half8, bu),
            acc, 0, 0, 0);
    }
    return acc;
}

// top-2 over the 14x16 lag tile: per-lane regs then 64-lane butterfly
__device__ __forceinline__ void top2(floatx4 acc, int qd, int nn,
                                     float& v1, int& i1, float& v2) {
    v1 = acc[0];
    i1 = 64*qd + nn;
    v2 = -__builtin_inff();
    #pragma unroll
    for (int r = 1; r < 4; ++r) {
        float cv = (4*qd + r < 14) ? acc[r] : -__builtin_inff();
        bool take = (cv > v1);
        float lose = take ? v1 : cv;
        if (take) { v1 = cv; i1 = 64*qd + 16*r + nn; }
        v2 = fmaxf(v2, lose);
    }
    #pragma unroll
    for (int m = 1; m < 64; m <<= 1) {
        float ov1 = __shfl_xor(v1, m);
        float ov2 = __shfl_xor(v2, m);
        int   oi1 = __shfl_xor(i1, m);
        bool take = (ov1 > v1) || (ov1 == v1 && oi1 < i1);
        float lose = take ? v1 : ov1;
        if (take) { v1 = ov1; i1 = oi1; }
        v2 = fmaxf(fmaxf(v2, ov2), lose);
    }
}

__device__ __forceinline__ void emit(float* out, int bf, int i1) {
    float period = (float)(i1 + MIN_PERIOD);
    float f0 = SR_F / (period + 1e-8f);
    out[bf] = fminf(fmaxf(f0, 50.0f), 500.0f);
}

__global__ void f0_zero() {
    if (threadIdx.x == 0) { g_cnt2 = 0u; g_cnt3 = 0u; }
}

// ===================== tier-1 kernel (hot, multi-frame) =====================
__global__ __launch_bounds__(256, 8) void f0_t1(const float* __restrict__ wav,
                                                float* __restrict__ out) {
    __shared__ unsigned int yw[A_WPB][800];   // 12.8 KB -> 6 blocks/CU resident
    const int tid  = threadIdx.x;
    const int wv   = tid >> 6;
    const int lane = tid & 63;
    unsigned int* ye = yw[wv];
    unsigned int* yo = ye + 400;

    // zero margins ONCE: payload dwords (e:[120,376), o:[119,376)) are fully
    // rewritten every frame; fast path always leaves hw751 of yo == 0.
    ye[lane] = 0u; yo[lane] = 0u;
    if (lane < 56) { ye[64 + lane] = 0u; yo[64 + lane] = 0u; }
    if (lane < 25) { ye[375 + lane] = 0u; yo[375 + lane] = 0u; }

    const int qd  = lane >> 4;
    const int nn  = lane & 15;
    const int par = nn & 1;
    const unsigned int* ybh = par ? yo : ye;
    const int wA0 = 120 + 4*qd - 8*nn;
    const int wB0 = 136 + 4*qd + ((nn - par) >> 1);

    // XCD-contiguous wave slot: XCD x (blockIdx%8) owns a contiguous run of
    // 192 block-slots -> contiguous ~5376-frame region (~5.4MB, L2-resident).
    const int cblk = (blockIdx.x & 7) * (A_BLOCKS / 8) + (blockIdx.x >> 3);
    const int s    = cblk * A_WPB + wv;

    for (int j = 0; j < A_CHUNK; ++j) {
        const int bf = s * A_CHUNK + j;
        if (bf >= TOTAL) break;
        const int b = bf / N_FRAMES;
        const int f = bf - b * N_FRAMES;
        const float* __restrict__ x = wav + (size_t)b * T_LEN;
        const int base = f * HOP - PAD;
        const bool fastp = (f != 0) && (f != N_FRAMES - 1);

        __threadfence_block();   // drain prev iter's LDS reads before overwrite
        float qen = 0.0f;
        if (fastp) {
            const float4* g4 = (const float4*)(x + base);   // aligned, in-bounds
            float4 c1 = g4[lane];
            float4 c2 = g4[lane + 64];
            qen = c1.x*c1.x + c1.y*c1.y + c1.z*c1.z + c1.w*c1.w
                + c2.x*c2.x + c2.y*c2.y + c2.z*c2.z + c2.w*c2.w;
            write_copies(ye, yo, pkh(c1.x, c1.y), pkh(c1.z, c1.w),
                                 pkh(c2.x, c2.y), pkh(c2.z, c2.w), lane);
        } else {
            for (int t = lane; t < FRAME_LEN; t += 64) {
                int idxr = base + t;
                if (idxr < 0) idxr = -idxr;
                if (idxr >= T_LEN) idxr = 2 * (T_LEN - 1) - idxr;
                float v = x[idxr];
                qen = __builtin_fmaf(v, v, qen);
                unsigned short h = __builtin_bit_cast(unsigned short, (_Float16)v);
                ((unsigned short*)ye)[240 + t] = h;
                ((unsigned short*)yo)[239 + t] = h;
            }
            if (lane == 0) ((unsigned short*)yo)[751] = 0;  // insurance vs stale
        }
        __threadfence_block();

        #pragma unroll
        for (int m = 1; m < 64; m <<= 1) qen += __shfl_xor(qen, m);

        floatx4 acc = mfma16_2chain(ye, ybh, wA0, wB0);

        float v1, v2; int i1;
        top2(acc, qd, nn, v1, i1, v2);

        const float E1 = 9.765625e-4f * qen + 0.05f;
        if (lane == 0) {
            if (v1 - v2 > 2.0f * E1) {
                emit(out, bf, i1);
            } else {
                unsigned int ii = atomicAdd(&g_cnt2, 1u);
                g_lst2[ii] = (unsigned int)bf;
            }
        }
    }
}

// ================== tier-2 kernel (double-f16 split, ~15%) ==================
__global__ __launch_bounds__(256, 3) void f0_t2(const float* __restrict__ wav,
                                                float* __restrict__ out) {
    __shared__ unsigned int yw[B_WPB][1600];   // 25.6 KB
    const int tid  = threadIdx.x;
    const int wv   = tid >> 6;
    const int lane = tid & 63;
    unsigned int* ye  = yw[wv];
    unsigned int* yo  = ye + 400;
    unsigned int* le  = ye + 800;
    unsigned int* loo = ye + 1200;

    // zero margins once (payload fully rewritten per item)
    ye[lane] = 0u; yo[lane] = 0u; le[lane] = 0u; loo[lane] = 0u;
    if (lane < 56) { ye[64+lane]=0u; yo[64+lane]=0u; le[64+lane]=0u; loo[64+lane]=0u; }
    if (lane < 25) { ye[375+lane]=0u; yo[375+lane]=0u; le[375+lane]=0u; loo[375+lane]=0u; }

    const int qd  = lane >> 4;
    const int nn  = lane & 15;
    const int par = nn & 1;
    const unsigned int* ybh = par ? yo : ye;
    const unsigned int* ybl = par ? loo : le;
    const int wA0 = 120 + 4*qd - 8*nn;
    const int wB0 = 136 + 4*qd + ((nn - par) >> 1);

    const unsigned int cnt = g_cnt2;
    for (unsigned int it = blockIdx.x * B_WPB + wv; it < cnt; it += B_WAVES) {
        const int bf = (int)g_lst2[it];
        const int b = bf / N_FRAMES;
        const int f = bf - b * N_FRAMES;
        const float* __restrict__ x = wav + (size_t)b * T_LEN;
        const int base = f * HOP - PAD;
        const bool fastp = (f != 0) && (f != N_FRAMES - 1);

        __threadfence_block();
        float qen = 0.0f;
        if (fastp) {
            const float4* g4 = (const float4*)(x + base);
            float4 c1 = g4[lane];
            float4 c2 = g4[lane + 64];
            qen = c1.x*c1.x + c1.y*c1.y + c1.z*c1.z + c1.w*c1.w
                + c2.x*c2.x + c2.y*c2.y + c2.z*c2.z + c2.w*c2.w;
            write_copies(ye, yo, pkh(c1.x, c1.y), pkh(c1.z, c1.w),
                                 pkh(c2.x, c2.y), pkh(c2.z, c2.w), lane);
            float l0 = c1.x - (float)(_Float16)c1.x;
            float l1 = c1.y - (float)(_Float16)c1.y;
            float l2 = c1.z - (float)(_Float16)c1.z;
            float l3 = c1.w - (float)(_Float16)c1.w;
            float l4 = c2.x - (float)(_Float16)c2.x;
            float l5 = c2.y - (float)(_Float16)c2.y;
            float l6 = c2.z - (float)(_Float16)c2.z;
            float l7 = c2.w - (float)(_Float16)c2.w;
            write_copies(le, loo, pkh(l0, l1), pkh(l2, l3),
                                  pkh(l4, l5), pkh(l6, l7), lane);
        } else {
            for (int t = lane; t < FRAME_LEN; t += 64) {
                int idxr = base + t;
                if (idxr < 0) idxr = -idxr;
                if (idxr >= T_LEN) idxr = 2 * (T_LEN - 1) - idxr;
                float v = x[idxr];
                qen = __builtin_fmaf(v, v, qen);
                float l = v - (float)(_Float16)v;
                unsigned short h  = __builtin_bit_cast(unsigned short, (_Float16)v);
                unsigned short hl = __builtin_bit_cast(unsigned short, (_Float16)l);
                ((unsigned short*)ye)[240 + t] = h;
                ((unsigned short*)yo)[239 + t] = h;
                ((unsigned short*)le)[240 + t] = hl;
                ((unsigned short*)loo)[239 + t] = hl;
            }
            if (lane == 0) {
                ((unsigned short*)yo)[751]  = 0;
                ((unsigned short*)loo)[751] = 0;
            }
        }
        __threadfence_block();

        #pragma unroll
        for (int m = 1; m < 64; m <<= 1) qen += __shfl_xor(qen, m);

        // exact r13 numerics: (acc0+acc1) then hi*lo chain then lo*hi chain
        floatx4 acc = mfma16_2chain(ye, ybh, wA0, wB0);
        acc = mfma16_chain(acc, ye, ybl, wA0, wB0);   // hi * lo
        acc = mfma16_chain(acc, le, ybh, wA0, wB0);   // lo * hi

        float v1, v2; int i1;
        top2(acc, qd, nn, v1, i1, v2);

        const float E2 = 1.0e-4f * qen + 0.02f;
        if (lane == 0) {
            if (v1 - v2 > 2.0f * E2) {
                emit(out, bf, i1);
            } else {
                unsigned int ii = atomicAdd(&g_cnt3, 1u);
                g_lst3[ii] = (unsigned int)bf;
            }
        }
    }
}

// ================== tier-3 kernel (fp64 exact, ~1-2%) ==================
__global__ __launch_bounds__(256, 2) void f0_t3(const float* __restrict__ wav,
                                                float* __restrict__ out) {
    __shared__ float swb[C_WPB][576];   // 9.2 KB
    const int tid  = threadIdx.x;
    const int wv   = tid >> 6;
    const int lane = tid & 63;
    float* sw = swb[wv];
    const int qd  = lane >> 4;
    const int seg = lane & 15;
    const bool s0 = (seg & 1), s1 = (seg & 2), s2 = (seg & 4), s3 = (seg & 8);

    const unsigned int cnt = g_cnt3;
    for (unsigned int it = blockIdx.x * C_WPB + wv; it < cnt; it += C_WAVES) {
        const int bf = (int)g_lst3[it];
        const int b = bf / N_FRAMES;
        const int f = bf - b * N_FRAMES;
        const float* __restrict__ x = wav + (size_t)b * T_LEN;
        const int base = f * HOP - PAD;
        const bool fastp = (f != 0) && (f != N_FRAMES - 1);

        __threadfence_block();
        if (fastp) {
            const float4* g4 = (const float4*)(x + base);
            ((float4*)sw)[swz(lane)]      = g4[lane];
            ((float4*)sw)[swz(lane + 64)] = g4[lane + 64];
            if (lane < 16) ((float4*)sw)[swz(lane + 128)] = make_float4(0.f,0.f,0.f,0.f);
        } else {
            for (int t = lane; t < FRAME_LEN; t += 64) {
                int idxr = base + t;
                if (idxr < 0) idxr = -idxr;
                if (idxr >= T_LEN) idxr = 2 * (T_LEN - 1) - idxr;
                sw[(swz(t >> 2) << 2) | (t & 3)] = x[idxr];
            }
            int t = FRAME_LEN + lane;
            sw[(swz(t >> 2) << 2) | (t & 3)] = 0.0f;
        }
        __threadfence_block();

        const float4* s4 = (const float4*)sw;
        double dtot[4];
        #pragma unroll
        for (int r = 0; r < 4; ++r) {
            const int g  = (r << 2) + qd;
            const int p0 = MIN_PERIOD + (g << 4);
            double dacc[16];
            #pragma unroll
            for (int j = 0; j < 16; ++j) dacc[j] = 0.0;
            if (g < 14) {
                const int n16 = (FRAME_LEN - p0 + 15) >> 4;
                #pragma unroll
                for (int k = 0; k < 2; ++k) {
                    const int ch = seg + (k << 4);
                    if (ch < n16) {
                        const int t  = ch << 4;
                        const int qa = t >> 2;
                        const int qw = (t + p0) >> 2;
                        float a[16], w[32];
                        #pragma unroll
                        for (int u = 0; u < 4; ++u) {
                            float4 v = s4[swz(qa + u)];
                            a[4*u+0]=v.x; a[4*u+1]=v.y; a[4*u+2]=v.z; a[4*u+3]=v.w;
                        }
                        #pragma unroll
                        for (int u = 0; u < 8; ++u) {
                            float4 v = s4[swz(qw + u)];
                            w[4*u+0]=v.x; w[4*u+1]=v.y; w[4*u+2]=v.z; w[4*u+3]=v.w;
                        }
                        #pragma unroll
                        for (int j = 0; j < 16; ++j) {
                            #pragma unroll
                            for (int i = 0; i < 16; ++i)
                                dacc[j] = fma((double)a[i], (double)w[i + j], dacc[j]);
                        }
                    }
                }
            }
            double u8[8], u4[4], u2[2], dtotal;
            #pragma unroll
            for (int i = 0; i < 8; ++i) {
                double lo = dacc[2*i], hi = dacc[2*i+1];
                double keep = s0 ? hi : lo, send = s0 ? lo : hi;
                u8[i] = keep + __shfl_xor(send, 1);
            }
            #pragma unroll
            for (int i = 0; i < 4; ++i) {
                double lo = u8[2*i], hi = u8[2*i+1];
                double keep = s1 ? hi : lo, send = s1 ? lo : hi;
                u4[i] = keep + __shfl_xor(send, 2);
            }
            #pragma unroll
            for (int i = 0; i < 2; ++i) {
                double lo = u4[2*i], hi = u4[2*i+1];
                double keep = s2 ? hi : lo, send = s2 ? lo : hi;
                u2[i] = keep + __shfl_xor(send, 4);
            }
            {
                double lo = u2[0], hi = u2[1];
                double keep = s3 ? hi : lo, send = s3 ? lo : hi;
                dtotal = keep + __shfl_xor(send, 8);
            }
            dtot[r] = ((r << 6) + lane < N_LAGS) ? dtotal : -__builtin_inf();
        }
        double dv1 = dtot[0];
        int    di1 = lane;
        #pragma unroll
        for (int r = 1; r < 4; ++r) {
            double c = dtot[r];
            if (c > dv1) { dv1 = c; di1 = (r << 6) + lane; }
        }
        #pragma unroll
        for (int m = 1; m < 64; m <<= 1) {
            double o = __shfl_xor(dv1, m);
            int   oi = __shfl_xor(di1, m);
            if (o > dv1 || (o == dv1 && oi < di1)) { dv1 = o; di1 = oi; }
        }
        if (lane == 0) emit(out, bf, di1);
    }
}

extern "C" void kernel_launch(void* const* d_in, const int* in_sizes, int n_in,
                              void* d_out, int out_size, void* d_ws, size_t ws_size,
                              hipStream_t stream) {
    const float* wav = (const float*)d_in[0]; // (64, 1, 163840) fp32
    float* out = (float*)d_out;               // (64, 641) fp32
    f0_zero<<<1, 64, 0, stream>>>();
    f0_t1<<<A_BLOCKS, 256, 0, stream>>>(wav, out);
    f0_t2<<<B_BLOCKS, 256, 0, stream>>>(wav, out);
    f0_t3<<<C_BLOCKS, 256, 0, stream>>>(wav, out);
}

// Round 2
// 135.722 us; speedup vs baseline: 1.3096x; 1.3096x over previous
//
#include <hip/hip_runtime.h>

// F0 via autocorrelation argmax — round 15: DS-pipe diet.
//   SR=16000, HOP=256, FRAME_LEN=512, pad=256, T=163840, B=64, n_frames=641
//   lags p in [32,256). argmax of RAW autocorrelation == reference argmax.
//
// Evidence r13 vs r14: 74 us @ occ 19% == 77 us @ occ 49%; VALU 16%, MFMA 5%,
// HBM 4%. The invariant shared resource is the per-CU LDS/DS pipe (~750 DS
// issue cycles/frame/wave: 16 b128 + 64 b32 B-reads + 26 shuffle ops).
// 160 frames/CU x 750cyc ~= 50us @ 100% DS busy -> measured 74-77. So: cut
// DS ops, revert to single straight-line kernel (r13 grid, no spills, no
// extra-kernel overhead).
//   - reductions (qen, top2): stages 1,2 via DPP quad_perm; 4,8 via DPP
//     row_ror (rotation-combine exact for commutative monoids); only 16,32
//     remain shuffles. 26 -> 8 DS ops/frame.
//   - B-frags: four 1-dword-staggered hi copies C_s[e]=y[e-240+s]; lane picks
//     s=nn&3 so its 8-elem slice is 8B-aligned -> 2x ds_read_b64 instead of
//     4x b32. C2/C3 are C0/C1's registers stored one dword earlier
//     (ds_write2_b32 pairs).
//   - c=15 step dropped: its B-frags are y[>=512]=0 -> contributes exactly
//     +0.0 -> bit-identical acc, 15 MFMAs not 16 (also in tier-2 chains).
// MFMA input VALUES are bit-identical to r13 -> tiers/gates unchanged.
//
// GEMM cast (validated r8-r14, absmax 0.0): y = frame zero-extended,
//   A[m,k]=y[k-16m], B[k,n]=y[k+32+n] => D[m,n]=AC[32+16m+n]
// Tiers: E1 = 2^-10*Q + 0.05 ; tier-2 double-f16 split E2 = 1e-4*Q + 0.02 ;
// tier-3 fp64 register tile exact (cold, ~1-2%).

#define SR_F 16000.0f
#define HOP 256
#define FRAME_LEN 512
#define PAD 256
#define T_LEN 163840
#define N_FRAMES 641
#define MIN_PERIOD 32
#define N_LAGS 224
#define WPB 4            // waves per block, one frame per wave
#define CP 402           // hi-copy stride in dwords
#define L0_OFF 1608      // lo even copy
#define L1_OFF 2008      // lo odd copy
#define WAVE_DW 2408     // dwords per wave slice (9632 B)
#define NC 15            // K-steps: c=15 contributes exactly zero

typedef _Float16 half8 __attribute__((ext_vector_type(8)));
typedef float floatx4 __attribute__((ext_vector_type(4)));

__device__ __forceinline__ int swz(int q) { return q ^ ((q >> 3) & 7); }

__device__ __forceinline__ unsigned int pkh(float a, float b) {
    unsigned short ha = __builtin_bit_cast(unsigned short, (_Float16)a);
    unsigned short hb = __builtin_bit_cast(unsigned short, (_Float16)b);
    return (unsigned int)ha | ((unsigned int)hb << 16);
}

// ---- DPP cross-lane (VALU pipe, not DS) ----
#define DPP_XOR1 0xB1    // quad_perm [1,0,3,2]
#define DPP_XOR2 0x4E    // quad_perm [2,3,0,1]
#define DPP_ROR4 0x124   // row_ror:4
#define DPP_ROR8 0x128   // row_ror:8

template <int CTRL> __device__ __forceinline__ int dppi(int x) {
    return __builtin_amdgcn_update_dpp(0, x, CTRL, 0xF, 0xF, false);
}
template <int CTRL> __device__ __forceinline__ float dppf(float x) {
    return __builtin_bit_cast(float, dppi<CTRL>(__builtin_bit_cast(int, x)));
}

// full-wave sum: quad xors, row rotations (exact: disjoint partials), shfl 16/32
__device__ __forceinline__ float wave_sum(float x) {
    x += dppf<DPP_XOR1>(x);
    x += dppf<DPP_XOR2>(x);
    x += dppf<DPP_ROR4>(x);
    x += dppf<DPP_ROR8>(x);
    x += __shfl_xor(x, 16);
    x += __shfl_xor(x, 32);
    return x;
}

template <int CTRL> __device__ __forceinline__
void top2_dpp(float& v1, int& i1, float& v2) {
    float ov1 = dppf<CTRL>(v1);
    int   oi1 = dppi<CTRL>(i1);
    float ov2 = dppf<CTRL>(v2);
    bool take = (ov1 > v1) || (ov1 == v1 && oi1 < i1);
    float lose = take ? v1 : ov1;
    if (take) { v1 = ov1; i1 = oi1; }
    v2 = fmaxf(fmaxf(v2, ov2), lose);
}

__device__ __forceinline__
void top2_shfl(float& v1, int& i1, float& v2, int m) {
    float ov1 = __shfl_xor(v1, m);
    float ov2 = __shfl_xor(v2, m);
    int   oi1 = __shfl_xor(i1, m);
    bool take = (ov1 > v1) || (ov1 == v1 && oi1 < i1);
    float lose = take ? v1 : ov1;
    if (take) { v1 = ov1; i1 = oi1; }
    v2 = fmaxf(fmaxf(v2, ov2), lose);
}

// per-lane top2 over 4 regs, then full-wave combine (monoid: exact any order)
__device__ __forceinline__
void top2_full(floatx4 acc, int qd, int nn, float& v1, int& i1, float& v2) {
    v1 = acc[0];
    i1 = 64*qd + nn;
    v2 = -__builtin_inff();
    #pragma unroll
    for (int r = 1; r < 4; ++r) {
        float cv = (4*qd + r < 14) ? acc[r] : -__builtin_inff();
        bool take = (cv > v1);
        float lose = take ? v1 : cv;
        if (take) { v1 = cv; i1 = 64*qd + 16*r + nn; }
        v2 = fmaxf(v2, lose);
    }
    top2_dpp<DPP_XOR1>(v1, i1, v2);
    top2_dpp<DPP_XOR2>(v1, i1, v2);
    top2_dpp<DPP_ROR4>(v1, i1, v2);
    top2_dpp<DPP_ROR8>(v1, i1, v2);
    top2_shfl(v1, i1, v2, 16);
    top2_shfl(v1, i1, v2, 32);
}

// stage 4 staggered hi copies: C_s[e] = y[e-240+s], s=0..3
__device__ __forceinline__ void write_hi4(unsigned int* c0_, unsigned int* c1_,
                                          unsigned int* c2_, unsigned int* c3_,
                                          unsigned int u10, unsigned int u11,
                                          unsigned int u20, unsigned int u21,
                                          int lane) {
    // C0: dword 120+2l = (y[4l],y[4l+1]) ...
    *(unsigned long long*)(c0_ + 120 + 2*lane) =
        ((unsigned long long)u11 << 32) | u10;
    *(unsigned long long*)(c0_ + 248 + 2*lane) =
        ((unsigned long long)u21 << 32) | u20;
    unsigned int a  = __shfl(u10, (lane + 1) & 63);
    unsigned int bb = __shfl(u20, (lane + 1) & 63);
    unsigned int n1 = (lane == 63) ? bb : a;
    unsigned int n2 = (lane == 63) ? 0u : bb;
    unsigned int o10 = (u10 >> 16) | (u11 << 16);
    unsigned int o11 = (u11 >> 16) | (n1 << 16);
    unsigned int o20 = (u20 >> 16) | (u21 << 16);
    unsigned int o21 = (u21 >> 16) | (n2 << 16);
    *(unsigned long long*)(c1_ + 120 + 2*lane) =
        ((unsigned long long)o11 << 32) | o10;
    *(unsigned long long*)(c1_ + 248 + 2*lane) =
        ((unsigned long long)o21 << 32) | o20;
    // C2 = C0 data one dword earlier (adjacent pairs -> ds_write2_b32)
    c2_[119 + 2*lane] = u10; c2_[120 + 2*lane] = u11;
    c2_[247 + 2*lane] = u20; c2_[248 + 2*lane] = u21;
    // C3 = C1 data one dword earlier
    c3_[119 + 2*lane] = o10; c3_[120 + 2*lane] = o11;
    c3_[247 + 2*lane] = o20; c3_[248 + 2*lane] = o21;
}

// stage lo parity copies (tier-2 only): L0[e]=y[e-240], L1[e]=y[e-239]
__device__ __forceinline__ void write_lo2(unsigned int* l0_, unsigned int* l1_,
                                          unsigned int u10, unsigned int u11,
                                          unsigned int u20, unsigned int u21,
                                          int lane) {
    *(unsigned long long*)(l0_ + 120 + 2*lane) =
        ((unsigned long long)u11 << 32) | u10;
    *(unsigned long long*)(l0_ + 248 + 2*lane) =
        ((unsigned long long)u21 << 32) | u20;
    unsigned int a  = __shfl(u10, (lane + 1) & 63);
    unsigned int bb = __shfl(u20, (lane + 1) & 63);
    unsigned int n1 = (lane == 63) ? bb : a;
    unsigned int n2 = (lane == 63) ? 0u : bb;
    *(unsigned long long*)(l1_ + 120 + 2*lane) =
        ((unsigned long long)(((u11 >> 16) | (n1 << 16))) << 32) |
        ((u10 >> 16) | (u11 << 16));
    *(unsigned long long*)(l1_ + 248 + 2*lane) =
        ((unsigned long long)(((u21 >> 16) | (n2 << 16))) << 32) |
        ((u20 >> 16) | (u21 << 16));
}

__global__ __launch_bounds__(256, 4) void f0_kernel(const float* __restrict__ wav,
                                                    float* __restrict__ out) {
    __shared__ unsigned int yw[WPB][WAVE_DW];   // 38528 B/block -> 4 blocks/CU

    const int tid  = threadIdx.x;
    const int wv   = tid >> 6;
    const int lane = tid & 63;
    unsigned int* c0p = yw[wv];
    unsigned int* c1p = c0p + CP;
    unsigned int* c2p = c0p + 2*CP;
    unsigned int* c3p = c0p + 3*CP;
    unsigned int* l0p = c0p + L0_OFF;
    unsigned int* l1p = c0p + L1_OFF;

    // XCD-contiguous frame assignment: 10256 blocks = 8*1282.
    const int xcd = blockIdx.x & 7;
    const int idx = blockIdx.x >> 3;
    const int bf  = (xcd * 1282 + idx) * WPB + wv;   // all 41024 covered
    const int b   = bf / N_FRAMES;
    const int f   = bf - b * N_FRAMES;
    const float* __restrict__ x = wav + (size_t)b * T_LEN;
    const int base = f * HOP - PAD;
    const bool fast = (f != 0 && f != N_FRAMES - 1);

    const int qd = lane >> 4;       // quad
    const int nn = lane & 15;       // A-row m / B-col n
    const int par = nn & 1;
    const int wA0 = 120 + 4*qd - 8*nn;                       // C0/L0, 16B align
    // hi B base: copy s=nn&3, dword 136 + 4qd + 2*(nn>>2) (8B aligned)
    const unsigned int* bhp = c0p + CP*(nn & 3) + 136 + 4*qd + 2*(nn >> 2);
    const int wB0old = 136 + 4*qd + ((nn - par) >> 1);       // lo parity copies
    const int seg = lane & 15;
    const bool s0 = (seg & 1), s1 = (seg & 2), s2 = (seg & 4), s3 = (seg & 8);

    // ---- issue global loads first ----
    float4 c1, c2;
    if (fast) {
        const float4* g4 = (const float4*)(x + base);   // aligned, in-bounds
        c1 = g4[lane];
        c2 = g4[lane + 64];
    }
    // one-time margin zeros (payloads rewritten below; same-wave DS order)
    for (int d = lane; d < 120; d += 64) { c0p[d] = 0u; l0p[d] = 0u; }
    if (lane < 28) {
        int d = 374 + lane;
        c0p[d] = 0u; c1p[d] = 0u; c2p[d] = 0u; c3p[d] = 0u;
        l0p[d] = 0u; l1p[d] = 0u;
    }

    float qen = 0.0f;
    if (fast) {
        qen = c1.x*c1.x + c1.y*c1.y + c1.z*c1.z + c1.w*c1.w
            + c2.x*c2.x + c2.y*c2.y + c2.z*c2.z + c2.w*c2.w;
        write_hi4(c0p, c1p, c2p, c3p, pkh(c1.x, c1.y), pkh(c1.z, c1.w),
                                      pkh(c2.x, c2.y), pkh(c2.z, c2.w), lane);
    } else {
        for (int t = lane; t < FRAME_LEN; t += 64) {
            int idxr = base + t;
            if (idxr < 0) idxr = -idxr;
            if (idxr >= T_LEN) idxr = 2 * (T_LEN - 1) - idxr;
            float v = x[idxr];
            qen = __builtin_fmaf(v, v, qen);
            unsigned short h = __builtin_bit_cast(unsigned short, (_Float16)v);
            ((unsigned short*)c0p)[240 + t] = h;
            ((unsigned short*)c1p)[239 + t] = h;
            ((unsigned short*)c2p)[238 + t] = h;
            ((unsigned short*)c3p)[237 + t] = h;
        }
    }
    __threadfence_block();

    qen = wave_sum(qen);

    // ---------------- tier-1: 15 MFMA (2 chains) ----------------
    floatx4 acc0 = {0.f, 0.f, 0.f, 0.f};
    floatx4 acc1 = {0.f, 0.f, 0.f, 0.f};
    #pragma unroll
    for (int c = 0; c < NC; ++c) {
        uint4 au = *(const uint4*)(c0p + (wA0 + 16*c));
        unsigned long long bl = *(const unsigned long long*)(bhp + 16*c);
        unsigned long long br = *(const unsigned long long*)(bhp + 16*c + 2);
        uint4 bu; bu.x = (unsigned int)bl; bu.y = (unsigned int)(bl >> 32);
        bu.z = (unsigned int)br; bu.w = (unsigned int)(br >> 32);
        if (c & 1)
            acc1 = __builtin_amdgcn_mfma_f32_16x16x32_f16(
                __builtin_bit_cast(half8, au), __builtin_bit_cast(half8, bu),
                acc1, 0, 0, 0);
        else
            acc0 = __builtin_amdgcn_mfma_f32_16x16x32_f16(
                __builtin_bit_cast(half8, au), __builtin_bit_cast(half8, bu),
                acc0, 0, 0, 0);
    }
    floatx4 acc = acc0 + acc1;

    float v1, v2; int i1;
    top2_full(acc, qd, nn, v1, i1, v2);

    const float E1 = 9.765625e-4f * qen + 0.05f;
    if (v1 - v2 > 2.0f * E1) {
        if (lane == 0) {
            float period = (float)(i1 + MIN_PERIOD);
            float f0 = SR_F / (period + 1e-8f);
            out[bf] = fminf(fmaxf(f0, 50.0f), 500.0f);
        }
        return;
    }

    // ==== tier-2: double-f16 split, +30 MFMA (hi*lo + lo*hi), ~15% ====
    if (fast) {
        float l0 = c1.x - (float)(_Float16)c1.x;
        float l1 = c1.y - (float)(_Float16)c1.y;
        float l2 = c1.z - (float)(_Float16)c1.z;
        float l3 = c1.w - (float)(_Float16)c1.w;
        float l4 = c2.x - (float)(_Float16)c2.x;
        float l5 = c2.y - (float)(_Float16)c2.y;
        float l6 = c2.z - (float)(_Float16)c2.z;
        float l7 = c2.w - (float)(_Float16)c2.w;
        write_lo2(l0p, l1p, pkh(l0, l1), pkh(l2, l3),
                            pkh(l4, l5), pkh(l6, l7), lane);
    } else {
        for (int t = lane; t < FRAME_LEN; t += 64) {
            int idxr = base + t;
            if (idxr < 0) idxr = -idxr;
            if (idxr >= T_LEN) idxr = 2 * (T_LEN - 1) - idxr;
            float v = x[idxr];
            float l = v - (float)(_Float16)v;
            unsigned short h = __builtin_bit_cast(unsigned short, (_Float16)l);
            ((unsigned short*)l0p)[240 + t] = h;
            ((unsigned short*)l1p)[239 + t] = h;
        }
    }
    __threadfence_block();

    const unsigned int* ybl = par ? l1p : l0p;
    #pragma unroll
    for (int c = 0; c < NC; ++c) {              // hi * lo
        uint4 au = *(const uint4*)(c0p + (wA0 + 16*c));
        const unsigned int* p = ybl + (wB0old + 16*c);
        uint4 bu; bu.x = p[0]; bu.y = p[1]; bu.z = p[2]; bu.w = p[3];
        acc = __builtin_amdgcn_mfma_f32_16x16x32_f16(
            __builtin_bit_cast(half8, au), __builtin_bit_cast(half8, bu),
            acc, 0, 0, 0);
    }
    #pragma unroll
    for (int c = 0; c < NC; ++c) {              // lo * hi
        uint4 au = *(const uint4*)(l0p + (wA0 + 16*c));
        unsigned long long bl = *(const unsigned long long*)(bhp + 16*c);
        unsigned long long br = *(const unsigned long long*)(bhp + 16*c + 2);
        uint4 bu; bu.x = (unsigned int)bl; bu.y = (unsigned int)(bl >> 32);
        bu.z = (unsigned int)br; bu.w = (unsigned int)(br >> 32);
        acc = __builtin_amdgcn_mfma_f32_16x16x32_f16(
            __builtin_bit_cast(half8, au), __builtin_bit_cast(half8, bu),
            acc, 0, 0, 0);
    }

    top2_full(acc, qd, nn, v1, i1, v2);

    const float E2 = 1.0e-4f * qen + 0.02f;
    if (v1 - v2 > 2.0f * E2) {
        if (lane == 0) {
            float period = (float)(i1 + MIN_PERIOD);
            float f0 = SR_F / (period + 1e-8f);
            out[bf] = fminf(fmaxf(f0, 50.0f), 500.0f);
        }
        return;
    }

    // ============ tier-3: fp64 register tile (exact), ~1-2% ============
    float* sw = (float*)c0p;   // 576 floats over C0/C1 (terminal use)
    if (fast) {
        const float4* g4 = (const float4*)(x + base);   // L2-hot reload
        ((float4*)sw)[swz(lane)]      = g4[lane];
        ((float4*)sw)[swz(lane + 64)] = g4[lane + 64];
        if (lane < 16) ((float4*)sw)[swz(lane + 128)] = make_float4(0.f,0.f,0.f,0.f);
    } else {
        for (int t = lane; t < FRAME_LEN; t += 64) {
            int idxr = base + t;
            if (idxr < 0) idxr = -idxr;
            if (idxr >= T_LEN) idxr = 2 * (T_LEN - 1) - idxr;
            sw[(swz(t >> 2) << 2) | (t & 3)] = x[idxr];
        }
        int t = FRAME_LEN + lane;
        sw[(swz(t >> 2) << 2) | (t & 3)] = 0.0f;
    }
    __threadfence_block();

    const float4* s4 = (const float4*)sw;
    double dtot[4];
    #pragma unroll
    for (int r = 0; r < 4; ++r) {
        const int g  = (r << 2) + qd;
        const int p0 = MIN_PERIOD + (g << 4);
        double dacc[16];
        #pragma unroll
        for (int j = 0; j < 16; ++j) dacc[j] = 0.0;
        if (g < 14) {
            const int n16 = (FRAME_LEN - p0 + 15) >> 4;
            #pragma unroll
            for (int k = 0; k < 2; ++k) {
                const int ch = seg + (k << 4);
                if (ch < n16) {
                    const int t  = ch << 4;
                    const int qa = t >> 2;
                    const int qw = (t + p0) >> 2;
                    float a[16], w[32];
                    #pragma unroll
                    for (int u = 0; u < 4; ++u) {
                        float4 v = s4[swz(qa + u)];
                        a[4*u+0]=v.x; a[4*u+1]=v.y; a[4*u+2]=v.z; a[4*u+3]=v.w;
                    }
                    #pragma unroll
                    for (int u = 0; u < 8; ++u) {
                        float4 v = s4[swz(qw + u)];
                        w[4*u+0]=v.x; w[4*u+1]=v.y; w[4*u+2]=v.z; w[4*u+3]=v.w;
                    }
                    #pragma unroll
                    for (int j = 0; j < 16; ++j) {
                        #pragma unroll
                        for (int i = 0; i < 16; ++i)
                            dacc[j] = fma((double)a[i], (double)w[i + j], dacc[j]);
                    }
                }
            }
        }
        double u8[8], u4[4], u2[2], dtotal;
        #pragma unroll
        for (int i = 0; i < 8; ++i) {
            double lo = dacc[2*i], hi = dacc[2*i+1];
            double keep = s0 ? hi : lo, send = s0 ? lo : hi;
            u8[i] = keep + __shfl_xor(send, 1);
        }
        #pragma unroll
        for (int i = 0; i < 4; ++i) {
            double lo = u8[2*i], hi = u8[2*i+1];
            double keep = s1 ? hi : lo, send = s1 ? lo : hi;
            u4[i] = keep + __shfl_xor(send, 2);
        }
        #pragma unroll
        for (int i = 0; i < 2; ++i) {
            double lo = u4[2*i], hi = u4[2*i+1];
            double keep = s2 ? hi : lo, send = s2 ? lo : hi;
            u2[i] = keep + __shfl_xor(send, 4);
        }
        {
            double lo = u2[0], hi = u2[1];
            double keep = s3 ? hi : lo, send = s3 ? lo : hi;
            dtotal = keep + __shfl_xor(send, 8);
        }
        dtot[r] = ((r << 6) + lane < N_LAGS) ? dtotal : -__builtin_inf();
    }
    double dv1 = dtot[0];
    int    di1 = lane;
    #pragma unroll
    for (int r = 1; r < 4; ++r) {
        double c = dtot[r];
        if (c > dv1) { dv1 = c; di1 = (r << 6) + lane; }
    }
    #pragma unroll
    for (int m = 1; m < 64; m <<= 1) {
        double o = __shfl_xor(dv1, m);
        int   oi = __shfl_xor(di1, m);
        if (o > dv1 || (o == dv1 && oi < di1)) { dv1 = o; di1 = oi; }
    }
    if (lane == 0) {
        float period = (float)(di1 + MIN_PERIOD);
        float f0 = SR_F / (period + 1e-8f);
        out[bf] = fminf(fmaxf(f0, 50.0f), 500.0f);
    }
}

extern "C" void kernel_launch(void* const* d_in, const int* in_sizes, int n_in,
                              void* d_out, int out_size, void* d_ws, size_t ws_size,
                              hipStream_t stream) {
    const float* wav = (const float*)d_in[0]; // (64, 1, 163840) fp32
    float* out = (float*)d_out;               // (64, 641) fp32
    const int n_blocks = (64 * N_FRAMES) / WPB;   // 10256 = 8 * 1282
    f0_kernel<<<n_blocks, 256, 0, stream>>>(wav, out);
}

// Round 3
// 130.339 us; speedup vs baseline: 1.3637x; 1.0413x over previous
//
#include <hip/hip_runtime.h>

// F0 via autocorrelation argmax — round 16: r13 layout + DS-shuffle purge.
//   SR=16000, HOP=256, FRAME_LEN=512, pad=256, T=163840, B=64, n_frames=641
//   lags p in [32,256). argmax of RAW autocorrelation == reference argmax.
//
// Evidence r13/r14/r15: throughput pinned at ~1 frame/1100cyc/CU regardless
// of occupancy (19% vs 49%), VALUBusy (16-29%), conflicts (0 vs 6.5M).
// Model: per-CU DS unit saturated (~800-1000 svc cyc/frame). r15's staggered
// copies traded shuffle savings for 4-way bank conflicts (even stride ->
// 16-bank lattice). r16 keeps r13's zero-conflict parity layout and removes
// ONLY the cross-lane DS ops: all reduction stages now VALU —
//   stages 1,2 quad_perm DPP; 4,8 row_ror DPP (validated r15);
//   stages 16,32 v_permlane16/32_swap_b32 (gfx950 VALU lane swap).
// Fail-safe: wrong swap orientation inflates v2 -> gates reject -> exact
// tier-3 computes output (slow, still correct). Sums use pr0+pr1 (orientation
// independent). NC=15 kept from r15 (c=15 B-frags all zero -> +0.0, bit-safe).
//
// GEMM cast (validated r8-r15, absmax 0.0): y = frame zero-extended,
//   A[m,k]=y[k-16m], B[k,n]=y[k+32+n] => D[m,n]=AC[32+16m+n]
//   15 mfma_f32_16x16x32_f16 (K=480+), two parity LDS copies for B-align.
// Tiers: E1 = 2^-10*Q + 0.05 ; tier-2 double-f16 split E2 = 1e-4*Q + 0.02 ;
// tier-3 fp64 register tile exact (cold).

#define SR_F 16000.0f
#define HOP 256
#define FRAME_LEN 512
#define PAD 256
#define T_LEN 163840
#define N_FRAMES 641
#define MIN_PERIOD 32
#define N_LAGS 224
#define WPB 4            // waves per block, one frame per wave
#define NC 15            // K-steps: c=15 contributes exactly zero

typedef _Float16 half8 __attribute__((ext_vector_type(8)));
typedef float floatx4 __attribute__((ext_vector_type(4)));
typedef unsigned int uint2v __attribute__((ext_vector_type(2)));

__device__ __forceinline__ int swz(int q) { return q ^ ((q >> 3) & 7); }

__device__ __forceinline__ unsigned int pkh(float a, float b) {
    unsigned short ha = __builtin_bit_cast(unsigned short, (_Float16)a);
    unsigned short hb = __builtin_bit_cast(unsigned short, (_Float16)b);
    return (unsigned int)ha | ((unsigned int)hb << 16);
}

// ---- cross-lane on the VALU pipe (keep the DS unit free) ----
#define DPP_XOR1 0xB1    // quad_perm [1,0,3,2]
#define DPP_XOR2 0x4E    // quad_perm [2,3,0,1]
#define DPP_ROR4 0x124   // row_ror:4
#define DPP_ROR8 0x128   // row_ror:8

template <int CTRL> __device__ __forceinline__ int dppi(int x) {
    return __builtin_amdgcn_update_dpp(0, x, CTRL, 0xF, 0xF, false);
}
template <int CTRL> __device__ __forceinline__ float dppf(float x) {
    return __builtin_bit_cast(float, dppi<CTRL>(__builtin_bit_cast(int, x)));
}

// permlane swaps: contract — pr[0]+pr[1] == self+partner;
// (sel ? pr[0] : pr[1]) == partner, sel = oddrow (16) / upper half (32).
__device__ __forceinline__ uint2v pl16sw(unsigned int x, bool sel) {
#if __has_builtin(__builtin_amdgcn_permlane16_swap)
    (void)sel;
    return __builtin_amdgcn_permlane16_swap(x, x, false, false);
#else
    unsigned int p = (unsigned int)__shfl_xor((int)x, 16);
    uint2v r; r[0] = sel ? p : x; r[1] = sel ? x : p; return r;
#endif
}
__device__ __forceinline__ uint2v pl32sw(unsigned int x, bool sel) {
#if __has_builtin(__builtin_amdgcn_permlane32_swap)
    (void)sel;
    return __builtin_amdgcn_permlane32_swap(x, x, false, false);
#else
    unsigned int p = (unsigned int)__shfl_xor((int)x, 32);
    uint2v r; r[0] = sel ? p : x; r[1] = sel ? x : p; return r;
#endif
}

// full-wave sum, zero DS ops
__device__ __forceinline__ float wave_sum(float x, bool oddrow, bool hihalf) {
    x += dppf<DPP_XOR1>(x);
    x += dppf<DPP_XOR2>(x);
    x += dppf<DPP_ROR4>(x);
    x += dppf<DPP_ROR8>(x);
    uint2v p = pl16sw(__builtin_bit_cast(unsigned int, x), oddrow);
    x = __builtin_bit_cast(float, p[0]) + __builtin_bit_cast(float, p[1]);
    p = pl32sw(__builtin_bit_cast(unsigned int, x), hihalf);
    x = __builtin_bit_cast(float, p[0]) + __builtin_bit_cast(float, p[1]);
    return x;
}

__device__ __forceinline__
void top2_comb(float& v1, int& i1, float& v2, float ov1, int oi1, float ov2) {
    bool take = (ov1 > v1) || (ov1 == v1 && oi1 < i1);
    float lose = take ? v1 : ov1;
    if (take) { v1 = ov1; i1 = oi1; }
    v2 = fmaxf(fmaxf(v2, ov2), lose);
}

template <int CTRL> __device__ __forceinline__
void top2_dpp(float& v1, int& i1, float& v2) {
    float ov1 = dppf<CTRL>(v1);
    int   oi1 = dppi<CTRL>(i1);
    float ov2 = dppf<CTRL>(v2);
    top2_comb(v1, i1, v2, ov1, oi1, ov2);
}

// per-lane top2 over 4 regs, then full-wave combine — zero DS ops
__device__ __forceinline__
void top2_full(floatx4 acc, int qd, int nn, bool oddrow, bool hihalf,
               float& v1, int& i1, float& v2) {
    v1 = acc[0];
    i1 = 64*qd + nn;
    v2 = -__builtin_inff();
    #pragma unroll
    for (int r = 1; r < 4; ++r) {
        float cv = (4*qd + r < 14) ? acc[r] : -__builtin_inff();
        bool take = (cv > v1);
        float lose = take ? v1 : cv;
        if (take) { v1 = cv; i1 = 64*qd + 16*r + nn; }
        v2 = fmaxf(v2, lose);
    }
    top2_dpp<DPP_XOR1>(v1, i1, v2);
    top2_dpp<DPP_XOR2>(v1, i1, v2);
    top2_dpp<DPP_ROR4>(v1, i1, v2);
    top2_dpp<DPP_ROR8>(v1, i1, v2);
    {   // stage 16 via permlane16_swap (partner select per contract)
        uint2v a = pl16sw(__builtin_bit_cast(unsigned int, v1), oddrow);
        uint2v b = pl16sw((unsigned int)i1, oddrow);
        uint2v c = pl16sw(__builtin_bit_cast(unsigned int, v2), oddrow);
        float ov1 = __builtin_bit_cast(float, oddrow ? a[0] : a[1]);
        int   oi1 = (int)(oddrow ? b[0] : b[1]);
        float ov2 = __builtin_bit_cast(float, oddrow ? c[0] : c[1]);
        top2_comb(v1, i1, v2, ov1, oi1, ov2);
    }
    {   // stage 32 via permlane32_swap
        uint2v a = pl32sw(__builtin_bit_cast(unsigned int, v1), hihalf);
        uint2v b = pl32sw((unsigned int)i1, hihalf);
        uint2v c = pl32sw(__builtin_bit_cast(unsigned int, v2), hihalf);
        float ov1 = __builtin_bit_cast(float, hihalf ? a[0] : a[1]);
        int   oi1 = (int)(hihalf ? b[0] : b[1]);
        float ov2 = __builtin_bit_cast(float, hihalf ? c[0] : c[1]);
        top2_comb(v1, i1, v2, ov1, oi1, ov2);
    }
}

// stage parity copies: even (elem e = Y[e-240]) + odd (elem e = Y[e-239])
__device__ __forceinline__ void write_copies(unsigned int* e, unsigned int* o,
                                             unsigned int u10, unsigned int u11,
                                             unsigned int u20, unsigned int u21,
                                             int lane) {
    e[120 + 2*lane] = u10;  e[121 + 2*lane] = u11;
    e[248 + 2*lane] = u20;  e[249 + 2*lane] = u21;
    unsigned int a  = __shfl(u10, (lane + 1) & 63);
    unsigned int bb = __shfl(u20, (lane + 1) & 63);
    unsigned int n1 = (lane == 63) ? bb : a;
    unsigned int n2 = (lane == 63) ? 0u : bb;
    o[120 + 2*lane] = (u10 >> 16) | (u11 << 16);
    o[121 + 2*lane] = (u11 >> 16) | (n1 << 16);
    o[248 + 2*lane] = (u20 >> 16) | (u21 << 16);
    o[249 + 2*lane] = (u21 >> 16) | (n2 << 16);
    if (lane == 0) o[119] = u10 << 16;   // {Y[-1]=0, Y[0]}
}

__global__ __launch_bounds__(256, 4) void f0_kernel(const float* __restrict__ wav,
                                                    float* __restrict__ out) {
    // per-wave slice: ye(400) yo(400) le(400) lo(400) dwords = 6400 B
    __shared__ unsigned int yw[WPB][1600];

    const int tid  = threadIdx.x;
    const int wv   = tid >> 6;
    const int lane = tid & 63;
    unsigned int* ye  = yw[wv];
    unsigned int* yo  = ye + 400;
    unsigned int* le  = ye + 800;
    unsigned int* loo = ye + 1200;

    // XCD-contiguous frame assignment: 10256 blocks = 8*1282.
    const int xcd = blockIdx.x & 7;
    const int idx = blockIdx.x >> 3;
    const int bf  = (xcd * 1282 + idx) * WPB + wv;   // all 41024 covered
    const int b   = bf / N_FRAMES;
    const int f   = bf - b * N_FRAMES;
    const float* __restrict__ x = wav + (size_t)b * T_LEN;
    const int base = f * HOP - PAD;
    const bool fast = (f != 0 && f != N_FRAMES - 1);

    const int qd = lane >> 4;       // quad
    const int nn = lane & 15;       // A-row m / B-col n
    const int par = nn & 1;
    const unsigned int* ybh = par ? yo : ye;
    const unsigned int* ybl = par ? loo : le;
    const int wA0 = 120 + 4*qd - 8*nn;
    const int wB0 = 136 + 4*qd + ((nn - par) >> 1);
    const int seg = lane & 15;
    const bool s0 = (seg & 1), s1 = (seg & 2), s2 = (seg & 4), s3 = (seg & 8);
    const bool oddrow = (lane & 16) != 0;
    const bool hihalf = (lane & 32) != 0;

    // ---- issue global loads first ----
    float4 c1, c2;
    if (fast) {
        const float4* g4 = (const float4*)(x + base);   // aligned, in-bounds
        c1 = g4[lane];
        c2 = g4[lane + 64];
    }
    // zero margins: dwords [0,120) and [375,400) of both parity copies
    ye[lane] = 0u; yo[lane] = 0u;
    if (lane < 56) { ye[64 + lane] = 0u; yo[64 + lane] = 0u; }
    if (lane < 25) { ye[375 + lane] = 0u; yo[375 + lane] = 0u; }

    float qen = 0.0f;
    if (fast) {
        qen = c1.x*c1.x + c1.y*c1.y + c1.z*c1.z + c1.w*c1.w
            + c2.x*c2.x + c2.y*c2.y + c2.z*c2.z + c2.w*c2.w;
        write_copies(ye, yo, pkh(c1.x, c1.y), pkh(c1.z, c1.w),
                             pkh(c2.x, c2.y), pkh(c2.z, c2.w), lane);
    } else {
        for (int t = lane; t < FRAME_LEN; t += 64) {
            int idxr = base + t;
            if (idxr < 0) idxr = -idxr;
            if (idxr >= T_LEN) idxr = 2 * (T_LEN - 1) - idxr;
            float v = x[idxr];
            qen = __builtin_fmaf(v, v, qen);
            unsigned short h = __builtin_bit_cast(unsigned short, (_Float16)v);
            ((unsigned short*)ye)[240 + t] = h;
            ((unsigned short*)yo)[239 + t] = h;
        }
    }
    __threadfence_block();

    qen = wave_sum(qen, oddrow, hihalf);

    // ---------------- tier-1: 15 MFMA (2 chains) ----------------
    floatx4 acc0 = {0.f, 0.f, 0.f, 0.f};
    floatx4 acc1 = {0.f, 0.f, 0.f, 0.f};
    #pragma unroll
    for (int c = 0; c < NC; ++c) {
        uint4 au = *(const uint4*)(ye + (wA0 + 16*c));
        const unsigned int* pb = ybh + (wB0 + 16*c);
        uint4 bu; bu.x = pb[0]; bu.y = pb[1]; bu.z = pb[2]; bu.w = pb[3];
        if (c & 1)
            acc1 = __builtin_amdgcn_mfma_f32_16x16x32_f16(
                __builtin_bit_cast(half8, au), __builtin_bit_cast(half8, bu),
                acc1, 0, 0, 0);
        else
            acc0 = __builtin_amdgcn_mfma_f32_16x16x32_f16(
                __builtin_bit_cast(half8, au), __builtin_bit_cast(half8, bu),
                acc0, 0, 0, 0);
    }
    floatx4 acc = acc0 + acc1;

    float v1, v2; int i1;
    top2_full(acc, qd, nn, oddrow, hihalf, v1, i1, v2);

    const float E1 = 9.765625e-4f * qen + 0.05f;
    if (v1 - v2 > 2.0f * E1) {
        if (lane == 0) {
            float period = (float)(i1 + MIN_PERIOD);
            float f0 = SR_F / (period + 1e-8f);
            out[bf] = fminf(fmaxf(f0, 50.0f), 500.0f);
        }
        return;
    }

    // ==== tier-2: double-f16 split, +30 MFMA (hi*lo + lo*hi), ~15% ====
    le[lane] = 0u; loo[lane] = 0u;
    if (lane < 56) { le[64 + lane] = 0u; loo[64 + lane] = 0u; }
    if (lane < 25) { le[375 + lane] = 0u; loo[375 + lane] = 0u; }
    if (fast) {
        float l0 = c1.x - (float)(_Float16)c1.x;
        float l1 = c1.y - (float)(_Float16)c1.y;
        float l2 = c1.z - (float)(_Float16)c1.z;
        float l3 = c1.w - (float)(_Float16)c1.w;
        float l4 = c2.x - (float)(_Float16)c2.x;
        float l5 = c2.y - (float)(_Float16)c2.y;
        float l6 = c2.z - (float)(_Float16)c2.z;
        float l7 = c2.w - (float)(_Float16)c2.w;
        write_copies(le, loo, pkh(l0, l1), pkh(l2, l3),
                              pkh(l4, l5), pkh(l6, l7), lane);
    } else {
        for (int t = lane; t < FRAME_LEN; t += 64) {
            int idxr = base + t;
            if (idxr < 0) idxr = -idxr;
            if (idxr >= T_LEN) idxr = 2 * (T_LEN - 1) - idxr;
            float v = x[idxr];
            float l = v - (float)(_Float16)v;
            unsigned short h = __builtin_bit_cast(unsigned short, (_Float16)l);
            ((unsigned short*)le)[240 + t] = h;
            ((unsigned short*)loo)[239 + t] = h;
        }
    }
    __threadfence_block();

    #pragma unroll
    for (int c = 0; c < NC; ++c) {              // hi * lo
        uint4 au = *(const uint4*)(ye + (wA0 + 16*c));
        const unsigned int* p = ybl + (wB0 + 16*c);
        uint4 bu; bu.x = p[0]; bu.y = p[1]; bu.z = p[2]; bu.w = p[3];
        acc = __builtin_amdgcn_mfma_f32_16x16x32_f16(
            __builtin_bit_cast(half8, au), __builtin_bit_cast(half8, bu),
            acc, 0, 0, 0);
    }
    #pragma unroll
    for (int c = 0; c < NC; ++c) {              // lo * hi
        uint4 au = *(const uint4*)(le + (wA0 + 16*c));
        const unsigned int* p = ybh + (wB0 + 16*c);
        uint4 bu; bu.x = p[0]; bu.y = p[1]; bu.z = p[2]; bu.w = p[3];
        acc = __builtin_amdgcn_mfma_f32_16x16x32_f16(
            __builtin_bit_cast(half8, au), __builtin_bit_cast(half8, bu),
            acc, 0, 0, 0);
    }

    top2_full(acc, qd, nn, oddrow, hihalf, v1, i1, v2);

    const float E2 = 1.0e-4f * qen + 0.02f;
    if (v1 - v2 > 2.0f * E2) {
        if (lane == 0) {
            float period = (float)(i1 + MIN_PERIOD);
            float f0 = SR_F / (period + 1e-8f);
            out[bf] = fminf(fmaxf(f0, 50.0f), 500.0f);
        }
        return;
    }

    // ============ tier-3: fp64 register tile (exact), ~1-2% ============
    float* sw = (float*)ye;   // 576 floats over ye+yo (terminal use)
    if (fast) {
        const float4* g4 = (const float4*)(x + base);   // L2-hot reload
        ((float4*)sw)[swz(lane)]      = g4[lane];
        ((float4*)sw)[swz(lane + 64)] = g4[lane + 64];
        if (lane < 16) ((float4*)sw)[swz(lane + 128)] = make_float4(0.f,0.f,0.f,0.f);
    } else {
        for (int t = lane; t < FRAME_LEN; t += 64) {
            int idxr = base + t;
            if (idxr < 0) idxr = -idxr;
            if (idxr >= T_LEN) idxr = 2 * (T_LEN - 1) - idxr;
            sw[(swz(t >> 2) << 2) | (t & 3)] = x[idxr];
        }
        int t = FRAME_LEN + lane;
        sw[(swz(t >> 2) << 2) | (t & 3)] = 0.0f;
    }
    __threadfence_block();

    const float4* s4 = (const float4*)sw;
    double dtot[4];
    #pragma unroll
    for (int r = 0; r < 4; ++r) {
        const int g  = (r << 2) + qd;
        const int p0 = MIN_PERIOD + (g << 4);
        double dacc[16];
        #pragma unroll
        for (int j = 0; j < 16; ++j) dacc[j] = 0.0;
        if (g < 14) {
            const int n16 = (FRAME_LEN - p0 + 15) >> 4;
            #pragma unroll
            for (int k = 0; k < 2; ++k) {
                const int ch = seg + (k << 4);
                if (ch < n16) {
                    const int t  = ch << 4;
                    const int qa = t >> 2;
                    const int qw = (t + p0) >> 2;
                    float a[16], w[32];
                    #pragma unroll
                    for (int u = 0; u < 4; ++u) {
                        float4 v = s4[swz(qa + u)];
                        a[4*u+0]=v.x; a[4*u+1]=v.y; a[4*u+2]=v.z; a[4*u+3]=v.w;
                    }
                    #pragma unroll
                    for (int u = 0; u < 8; ++u) {
                        float4 v = s4[swz(qw + u)];
                        w[4*u+0]=v.x; w[4*u+1]=v.y; w[4*u+2]=v.z; w[4*u+3]=v.w;
                    }
                    #pragma unroll
                    for (int j = 0; j < 16; ++j) {
                        #pragma unroll
                        for (int i = 0; i < 16; ++i)
                            dacc[j] = fma((double)a[i], (double)w[i + j], dacc[j]);
                    }
                }
            }
        }
        double u8[8], u4[4], u2[2], dtotal;
        #pragma unroll
        for (int i = 0; i < 8; ++i) {
            double lo = dacc[2*i], hi = dacc[2*i+1];
            double keep = s0 ? hi : lo, send = s0 ? lo : hi;
            u8[i] = keep + __shfl_xor(send, 1);
        }
        #pragma unroll
        for (int i = 0; i < 4; ++i) {
            double lo = u8[2*i], hi = u8[2*i+1];
            double keep = s1 ? hi : lo, send = s1 ? lo : hi;
            u4[i] = keep + __shfl_xor(send, 2);
        }
        #pragma unroll
        for (int i = 0; i < 2; ++i) {
            double lo = u4[2*i], hi = u4[2*i+1];
            double keep = s2 ? hi : lo, send = s2 ? lo : hi;
            u2[i] = keep + __shfl_xor(send, 4);
        }
        {
            double lo = u2[0], hi = u2[1];
            double keep = s3 ? hi : lo, send = s3 ? lo : hi;
            dtotal = keep + __shfl_xor(send, 8);
        }
        dtot[r] = ((r << 6) + lane < N_LAGS) ? dtotal : -__builtin_inf();
    }
    double dv1 = dtot[0];
    int    di1 = lane;
    #pragma unroll
    for (int r = 1; r < 4; ++r) {
        double c = dtot[r];
        if (c > dv1) { dv1 = c; di1 = (r << 6) + lane; }
    }
    #pragma unroll
    for (int m = 1; m < 64; m <<= 1) {
        double o = __shfl_xor(dv1, m);
        int   oi = __shfl_xor(di1, m);
        if (o > dv1 || (o == dv1 && oi < di1)) { dv1 = o; di1 = oi; }
    }
    if (lane == 0) {
        float period = (float)(di1 + MIN_PERIOD);
        float f0 = SR_F / (period + 1e-8f);
        out[bf] = fminf(fmaxf(f0, 50.0f), 500.0f);
    }
}

extern "C" void kernel_launch(void* const* d_in, const int* in_sizes, int n_in,
                              void* d_out, int out_size, void* d_ws, size_t ws_size,
                              hipStream_t stream) {
    const float* wav = (const float*)d_in[0]; // (64, 1, 163840) fp32
    float* out = (float*)d_out;               // (64, 641) fp32
    const int n_blocks = (64 * N_FRAMES) / WPB;   // 10256 = 8 * 1282
    f0_kernel<<<n_blocks, 256, 0, stream>>>(wav, out);
}